// Round 6
// baseline (877.226 us; speedup 1.0000x reference)
//
#include <hip/hip_runtime.h>
#include <hip/hip_bf16.h>
#include <stdint.h>

#define M_DIM 4096
#define K_DIM 4096
#define N_DIM 11008
#define BKP 32                  // k per phase
#define NPH (K_DIM / BKP)       // 128 phases

#define AS1 __attribute__((address_space(1)))
#define AS3 __attribute__((address_space(3)))

typedef __bf16 bf16_t;
typedef __bf16 bf16x8 __attribute__((ext_vector_type(8)));
typedef float floatx4 __attribute__((ext_vector_type(4)));
typedef int   intx4  __attribute__((ext_vector_type(4)));

// ---------------------------------------------------------------------------
// k_prescale: xs[m, perm(k)] = bf16(x[m,k] * s[k/64]);
//             crow[m] = sum_k float(xs) * (zp[g] + 136)
// One wave per row; k-permutation (0,2,4,6,1,3,5,7) within each aligned
// 8-group matches the register-unpacked B fragment order in k_gemm.
// ---------------------------------------------------------------------------
__global__ __launch_bounds__(256) void k_prescale(
    const float* __restrict__ x,
    const float* __restrict__ scales,
    const float* __restrict__ zps,
    bf16_t* __restrict__ xs,
    float* __restrict__ crow)
{
    const int wid  = (blockIdx.x << 2) | (threadIdx.x >> 6);  // wave id = row
    const int lane = threadIdx.x & 63;
    const float4* xr = (const float4*)(x + (size_t)wid * K_DIM);
    bf16x8* xo = (bf16x8*)(xs + (size_t)wid * K_DIM);
    float acc = 0.f;
#pragma unroll
    for (int j = 0; j < 8; ++j) {
        const int idx = j * 64 + lane;        // 8-elem group index (512/row)
        const int g = idx >> 3;               // 64 elems per quant group
        const float s = scales[g];
        const float tz = zps[g] + 136.0f;
        const float4 v0 = xr[2 * idx];
        const float4 v1 = xr[2 * idx + 1];
        bf16x8 o;
        o[0] = (bf16_t)(v0.x * s);  // k+0
        o[1] = (bf16_t)(v0.z * s);  // k+2
        o[2] = (bf16_t)(v1.x * s);  // k+4
        o[3] = (bf16_t)(v1.z * s);  // k+6
        o[4] = (bf16_t)(v0.y * s);  // k+1
        o[5] = (bf16_t)(v0.w * s);  // k+3
        o[6] = (bf16_t)(v1.y * s);  // k+5
        o[7] = (bf16_t)(v1.w * s);  // k+7
        xo[idx] = o;
        float ssum = 0.f;
#pragma unroll
        for (int jj = 0; jj < 8; ++jj) ssum += (float)o[jj];
        acc += ssum * tz;
    }
#pragma unroll
    for (int off = 32; off > 0; off >>= 1) acc += __shfl_down(acc, off, 64);
    if (lane == 0) crow[wid] = acc;
}

// ---------------------------------------------------------------------------
// k_gemm — 4-deep counted-vmcnt phase pipeline (T3+T4) + T5 setprio.
//   out[m,n] = sum_k xs[m,k]*(w4[n,k]+136) + bias[n] - crow[m]
// Block tile 256x128, 4 waves 2(m)x2(n), wave tile 128x64.
// K split into 128 phases of K=32. A: 4 LDS buffers x 256x32 bf16 (16 KB
// each). Phase p computes buf p&3, stages buf (p+3)&3 via DMA, loads B(p+1)
// (plain compiler-tracked loads, issue order pinned).
//
// R6 changes vs r5 (which measured 2.25e7 bank conflicts + FETCH +20%):
//  - LDS slab swizzle (rule #21, both sides): DMA dest stays LINEAR; the
//    per-lane GLOBAL source is pre-permuted (m173) and the ds_read address
//    applies the matching swizzle. Within each 1024-B slab (16 rows x 64 B):
//    window w = row>>1 (128 B), slot s = (row&1)*4 + chunk, phys slot
//    sp = (s+w)&7. Read: lane(fm,quad) -> byte (fm>>1)*128 +
//    (((fm&1)*4+quad+(fm>>1))&7)*16. Quarter-wave hits every 4-bank group
//    exactly 2x (2-way = free per m136); r5's layout was 8-way.
//  - XCD swizzle REVERTED (r5: it cached 1.4 MB of B at the cost of
//    streaming 32 MB of A per XCD; natural x-fastest order keeps A (2 MB)
//    L2-resident and Bp (90 MB) L3-resident — r2's proven mapping).
//
// vmcnt queue at phase p's manual wait (B first, then 4 DMAs, pinned):
//   oldest→newest: DMA(p+1)x4 | B(p)x4 | DMA(p+2)x4 | B(p+1)x4 | DMA(p+3)x4
//   vmcnt(12) drains DMA(p+1) + B(p). DMA gets 3 phases of cover, B one.
// Prologue: B(0), DMA(0..2), one full drain + barrier (cross-wave ready).
// Rule #18 after every manual waitcnt.
// ---------------------------------------------------------------------------
__device__ __forceinline__ bf16x8 unpack_b(intx4 v)
{
    const uint32_t kMag = 0x43434343u;
    uint32_t p0 = __builtin_amdgcn_perm((uint32_t)v.y, (uint32_t)v.x, 0x0C0C0400u); // [b0,b1,0,0]
    uint32_t p1 = __builtin_amdgcn_perm((uint32_t)v.w, (uint32_t)v.z, 0x04000C0Cu); // [0,0,b2,b3]
    uint32_t bb = (p0 | p1) ^ 0x88888888u;          // nibbles n^8
    uint32_t lo = bb & 0x0F0F0F0Fu;                 // even-k weights
    uint32_t hi = (bb >> 4) & 0x0F0F0F0Fu;          // odd-k weights
    union { uint4 u; bf16x8 f; } o;
    o.u.x = __builtin_amdgcn_perm(kMag, lo, 0x04010400u);  // (k0,k2)+136
    o.u.y = __builtin_amdgcn_perm(kMag, lo, 0x04030402u);  // (k4,k6)+136
    o.u.z = __builtin_amdgcn_perm(kMag, hi, 0x04010400u);  // (k1,k3)+136
    o.u.w = __builtin_amdgcn_perm(kMag, hi, 0x04030402u);  // (k5,k7)+136
    return o.f;
}

#define DSR(D, AD, OFF) \
    asm volatile("ds_read_b128 %0, %1 offset:" OFF : "=v"(D) : "v"(AD))

#define PHASE(J, BPC, BPN, WOFF, O0,O1,O2,O3,O4,O5,O6,O7)                     \
    {                                                                         \
        __builtin_amdgcn_s_barrier();                                         \
        asm volatile("" ::: "memory");                                        \
        const int pB = (kb + (J) + 1) & (NPH - 1);                            \
        _Pragma("unroll")                                                     \
        for (int ni = 0; ni < 4; ++ni)                                        \
            BPN[ni] = *(const intx4*)(Bp + bOff[ni] + pB * 16);               \
        __builtin_amdgcn_sched_barrier(0);                                    \
        const int pA = (kb + (J) + 3) & (NPH - 1);                            \
        _Pragma("unroll")                                                     \
        for (int i = 0; i < 4; ++i)                                           \
            __builtin_amdgcn_global_load_lds(                                 \
                (const AS1 void*)(Agp + (size_t)i * 262144 + (size_t)pA * 32),\
                (AS3 void*)(sA + (WOFF) + i * 2048 + wave * 512), 16, 0, 0);  \
        asm volatile("s_waitcnt vmcnt(12)" ::: "memory");                     \
        __builtin_amdgcn_sched_barrier(0);                                    \
        intx4 afr[8];                                                         \
        DSR(afr[0], dsBase, O0); DSR(afr[1], dsBase, O1);                     \
        DSR(afr[2], dsBase, O2); DSR(afr[3], dsBase, O3);                     \
        DSR(afr[4], dsBase, O4); DSR(afr[5], dsBase, O5);                     \
        DSR(afr[6], dsBase, O6); DSR(afr[7], dsBase, O7);                     \
        bf16x8 bfr[4];                                                        \
        _Pragma("unroll")                                                     \
        for (int ni = 0; ni < 4; ++ni) bfr[ni] = unpack_b(BPC[ni]);           \
        asm volatile("s_waitcnt lgkmcnt(4)" ::: "memory");                    \
        __builtin_amdgcn_sched_barrier(0);                                    \
        __builtin_amdgcn_s_setprio(1);                                        \
        _Pragma("unroll")                                                     \
        for (int mi = 0; mi < 4; ++mi) {                                      \
            const bf16x8 af = __builtin_bit_cast(bf16x8, afr[mi]);            \
            _Pragma("unroll")                                                 \
            for (int ni = 0; ni < 4; ++ni)                                    \
                acc[mi][ni] = __builtin_amdgcn_mfma_f32_16x16x32_bf16(        \
                    af, bfr[ni], acc[mi][ni], 0, 0, 0);                       \
        }                                                                     \
        asm volatile("s_waitcnt lgkmcnt(0)" ::: "memory");                    \
        __builtin_amdgcn_sched_barrier(0);                                    \
        _Pragma("unroll")                                                     \
        for (int mi = 4; mi < 8; ++mi) {                                      \
            const bf16x8 af = __builtin_bit_cast(bf16x8, afr[mi]);            \
            _Pragma("unroll")                                                 \
            for (int ni = 0; ni < 4; ++ni)                                    \
                acc[mi][ni] = __builtin_amdgcn_mfma_f32_16x16x32_bf16(        \
                    af, bfr[ni], acc[mi][ni], 0, 0, 0);                       \
        }                                                                     \
        __builtin_amdgcn_s_setprio(0);                                        \
    }

__global__ __launch_bounds__(256, 2) void k_gemm(
    const bf16_t* __restrict__ A,     // xs [M][K] bf16 (k-permuted in 8-groups)
    const int* __restrict__ Bp,       // packed_w [N][K/2] int32 (low byte)
    const float* __restrict__ bias,
    const float* __restrict__ crow,
    float* __restrict__ out)
{
    __shared__ bf16_t sA[4 * 256 * BKP];   // 4 bufs x 16 KB = 64 KB

    const int t = threadIdx.x;
    const int wave = t >> 6;
    const int lane = t & 63;
    const int fm = lane & 15;
    const int quad = lane >> 4;

    // natural mapping (r2 control): x-fastest -> co-resident blocks share the
    // M-tile (A 2 MB L2-resident per XCD); Bp (90 MB) lives in L3.
    const int nBase = blockIdx.x * 128;
    const int mBase = blockIdx.y * 256;

    // A staging with pre-swizzled global source (LDS dest stays linear).
    // DMA i of wave wv fills slab (i*4+wv) (1024 B = 16 rows x 64 B).
    // Lane l writes slab byte l*16 = window w*128 + slot sp*16 (w=l>>3,
    // sp=l&7); that phys slot must hold logical s=(sp-w)&7 ->
    // row r = 2w + (s>>2), chunk c = s&3 of the slab.
    const int wL = lane >> 3;
    const int sL = ((lane & 7) - wL) & 7;
    const int rL = 2 * wL + (sL >> 2);
    const int cL = sL & 3;
    const uint32_t gAbase =
        (uint32_t)(mBase + wave * 16 + rL) * K_DIM + (uint32_t)(cL << 3);
    const bf16_t* Agp = A + gAbase;     // + i*64 rows (=i*262144) + phase*32

    const int wm = (wave >> 1) * 128;
    const int wn = (wave & 1) * 64;

    // B fragment row offsets (int32 units)
    int bOff[4];
#pragma unroll
    for (int ni = 0; ni < 4; ++ni)
        bOff[ni] = (nBase + wn + ni * 16 + fm) * (K_DIM / 2) + quad * 4;

    // ds_read base: lane(fm,quad) wants slab row fm, chunk quad ->
    // w = fm>>1, s = (fm&1)*4+quad, sp = (s+w)&7;
    // byte = wm*64 + w*128 + sp*16 (+ mi*1024 + buf*16384 immediates).
    const int wR = fm >> 1;
    const int spR = (((fm & 1) * 4 + quad) + wR) & 7;
    const uint32_t dsBase =
        (uint32_t)(size_t)(AS3 bf16_t*)sA +
        (uint32_t)(wm * 64 + wR * 128 + spR * 16);

    floatx4 acc[8][4];
#pragma unroll
    for (int mi = 0; mi < 8; ++mi)
#pragma unroll
        for (int ni = 0; ni < 4; ++ni)
            acc[mi][ni] = (floatx4){0.f, 0.f, 0.f, 0.f};

    intx4 bpA[4], bpB[4];

    // ---- prologue: B(0) first (plain loads), DMA tiles 0,1,2, then ONE
    //      full drain + barrier (cross-wave completion for bufs 0-2).
#pragma unroll
    for (int ni = 0; ni < 4; ++ni)
        bpA[ni] = *(const intx4*)(Bp + bOff[ni]);
    __builtin_amdgcn_sched_barrier(0);
#pragma unroll
    for (int pp = 0; pp < 3; ++pp)
#pragma unroll
        for (int i = 0; i < 4; ++i)
            __builtin_amdgcn_global_load_lds(
                (const AS1 void*)(Agp + (size_t)i * 262144 + (size_t)pp * 32),
                (AS3 void*)(sA + pp * 8192 + i * 2048 + wave * 512), 16, 0, 0);
    asm volatile("s_waitcnt vmcnt(0) lgkmcnt(0)" ::: "memory");
    __builtin_amdgcn_sched_barrier(0);
    __builtin_amdgcn_s_barrier();
    asm volatile("" ::: "memory");

    // ---- main loop: 128 phases, 4 per iteration (static buf/reg indices) --
#pragma unroll 1
    for (int kb = 0; kb < NPH; kb += 4) {
        PHASE(0, bpA, bpB, 24576, "0","1024","2048","3072","4096","5120","6144","7168")
        PHASE(1, bpB, bpA, 0,     "16384","17408","18432","19456","20480","21504","22528","23552")
        PHASE(2, bpA, bpB, 8192,  "32768","33792","34816","35840","36864","37888","38912","39936")
        PHASE(3, bpB, bpA, 16384, "49152","50176","51200","52224","53248","54272","55296","56320")
    }

    // epilogue: + bias[n] - crow[m]; C/D map: col=lane&15, row=quad*4+reg
    // nontemporal stores: keep the out-stream from evicting Bp in LLC
#pragma unroll
    for (int mi = 0; mi < 8; ++mi) {
        const int m0 = mBase + wm + mi * 16 + quad * 4;
        float cr[4];
#pragma unroll
        for (int r = 0; r < 4; ++r) cr[r] = crow[m0 + r];
#pragma unroll
        for (int ni = 0; ni < 4; ++ni) {
            const int n = nBase + wn + ni * 16 + fm;
            const float bn = bias[n];
#pragma unroll
            for (int r = 0; r < 4; ++r)
                __builtin_nontemporal_store(acc[mi][ni][r] + bn - cr[r],
                                            &out[(size_t)(m0 + r) * N_DIM + n]);
        }
    }
}

// ---------------------------------------------------------------------------
extern "C" void kernel_launch(void* const* d_in, const int* in_sizes, int n_in,
                              void* d_out, int out_size, void* d_ws, size_t ws_size,
                              hipStream_t stream)
{
    const float* x      = (const float*)d_in[0];
    const int*   pw     = (const int*)d_in[1];
    const float* scales = (const float*)d_in[2];
    const float* zps    = (const float*)d_in[3];
    const float* bias   = (const float*)d_in[4];
    float* out = (float*)d_out;

    char* ws = (char*)d_ws;
    bf16_t* xs   = (bf16_t*)ws;               // 4096*4096*2 = 33554432 B
    float*  crow = (float*)(ws + 33554432);   // 4096*4      = 16384 B

    hipLaunchKernelGGL(k_prescale, dim3(M_DIM / 4), dim3(256), 0, stream,
                       x, scales, zps, xs, crow);
    hipLaunchKernelGGL(k_gemm, dim3(N_DIM / 128, M_DIM / 256), dim3(256), 0, stream,
                       (const bf16_t*)xs, pw, bias, crow, out);
}

// Round 8
// 815.213 us; speedup vs baseline: 1.0761x; 1.0761x over previous
//
#include <hip/hip_runtime.h>
#include <hip/hip_bf16.h>
#include <stdint.h>

#define M_DIM 4096
#define K_DIM 4096
#define N_DIM 11008
#define BKP 32                  // k per phase
#define NPH (K_DIM / BKP)       // 128 phases

#define AS1 __attribute__((address_space(1)))
#define AS3 __attribute__((address_space(3)))

typedef __bf16 bf16_t;
typedef __bf16 bf16x8 __attribute__((ext_vector_type(8)));
typedef float floatx4 __attribute__((ext_vector_type(4)));
typedef int   intx4  __attribute__((ext_vector_type(4)));

// ---------------------------------------------------------------------------
// k_prescale: xs[m, perm(k)] = bf16(x[m,k] * s[k/64]);
//             crow[m] = sum_k float(xs) * (zp[g] + 136)
// One wave per row; k-permutation (0,2,4,6,1,3,5,7) within each aligned
// 8-group matches the register-unpacked B fragment order in the GEMMs.
// ---------------------------------------------------------------------------
__global__ __launch_bounds__(256) void k_prescale(
    const float* __restrict__ x,
    const float* __restrict__ scales,
    const float* __restrict__ zps,
    bf16_t* __restrict__ xs,
    float* __restrict__ crow)
{
    const int wid  = (blockIdx.x << 2) | (threadIdx.x >> 6);  // wave id = row
    const int lane = threadIdx.x & 63;
    const float4* xr = (const float4*)(x + (size_t)wid * K_DIM);
    bf16x8* xo = (bf16x8*)(xs + (size_t)wid * K_DIM);
    float acc = 0.f;
#pragma unroll
    for (int j = 0; j < 8; ++j) {
        const int idx = j * 64 + lane;        // 8-elem group index (512/row)
        const int g = idx >> 3;               // 64 elems per quant group
        const float s = scales[g];
        const float tz = zps[g] + 136.0f;
        const float4 v0 = xr[2 * idx];
        const float4 v1 = xr[2 * idx + 1];
        bf16x8 o;
        o[0] = (bf16_t)(v0.x * s);  // k+0
        o[1] = (bf16_t)(v0.z * s);  // k+2
        o[2] = (bf16_t)(v1.x * s);  // k+4
        o[3] = (bf16_t)(v1.z * s);  // k+6
        o[4] = (bf16_t)(v0.y * s);  // k+1
        o[5] = (bf16_t)(v0.w * s);  // k+3
        o[6] = (bf16_t)(v1.y * s);  // k+5
        o[7] = (bf16_t)(v1.w * s);  // k+7
        xo[idx] = o;
        float ssum = 0.f;
#pragma unroll
        for (int jj = 0; jj < 8; ++jj) ssum += (float)o[jj];
        acc += ssum * tz;
    }
#pragma unroll
    for (int off = 32; off > 0; off >>= 1) acc += __shfl_down(acc, off, 64);
    if (lane == 0) crow[wid] = acc;
}

// ---------------------------------------------------------------------------
// k_repack: Bp int32[N][2048] (one useful low byte each) -> B2 uint8[N][2048]
// byte = lowbyte(int32) ^ 0x88; within each 32-byte group (64 k) reorder
// [kh][q][j] -> [q][kh][j] so a GEMM lane's per-phase fragment is ONE dword.
// ONLY launched when ws_size is large enough (see kernel_launch guard).
// ---------------------------------------------------------------------------
__global__ __launch_bounds__(256) void k_repack(
    const int* __restrict__ Bp,
    uint8_t* __restrict__ B2)
{
    const int tid = blockIdx.x * 256 + threadIdx.x;   // 704512 total
    const int row = tid >> 6;
    const int g = tid & 63;
    const intx4* src = (const intx4*)(Bp + (size_t)row * 2048 + g * 32);
    intx4 a[8];
#pragma unroll
    for (int i = 0; i < 8; ++i) a[i] = src[i];
    uint32_t d[8];
#pragma unroll
    for (int dd = 0; dd < 8; ++dd) {
        const intx4 v = a[(dd & 1) * 4 + (dd >> 1)];
        uint32_t p0 = __builtin_amdgcn_perm((uint32_t)v.y, (uint32_t)v.x, 0x0C0C0400u); // [b0,b1,0,0]
        uint32_t p1 = __builtin_amdgcn_perm((uint32_t)v.w, (uint32_t)v.z, 0x04000C0Cu); // [0,0,b2,b3]
        d[dd] = (p0 | p1) ^ 0x88888888u;
    }
    uint8_t* dst = B2 + (size_t)row * 2048 + g * 32;
    *(intx4*)dst        = (intx4){(int)d[0], (int)d[1], (int)d[2], (int)d[3]};
    *(intx4*)(dst + 16) = (intx4){(int)d[4], (int)d[5], (int)d[6], (int)d[7]};
}

// ---------------------------------------------------------------------------
// Shared pieces for both GEMM variants (schedule identical to r6, which ran
// clean: conflicts 0, VGPR 124). 4-deep counted-vmcnt phase pipeline (T3+T4)
// + T5 setprio. Block tile 256x128, 4 waves 2(m)x2(n). A: 4 LDS bufs x 16 KB,
// slab-swizzled (DMA dest linear, global source pre-permuted, ds_read
// applies matching swizzle — r6-verified conflict-free). vmcnt(12) at each
// phase leaves 12 newest ops in flight (DMA 3 phases of cover, B one).
// ---------------------------------------------------------------------------
__device__ __forceinline__ bf16x8 unpack_b2(uint32_t b)   // b pre-XORed ^0x88
{
    const uint32_t kMag = 0x43434343u;
    uint32_t lo = b & 0x0F0F0F0Fu;
    uint32_t hi = (b >> 4) & 0x0F0F0F0Fu;
    union { uint4 u; bf16x8 f; } o;
    o.u.x = __builtin_amdgcn_perm(kMag, lo, 0x04010400u);  // (k0,k2)+136
    o.u.y = __builtin_amdgcn_perm(kMag, lo, 0x04030402u);  // (k4,k6)+136
    o.u.z = __builtin_amdgcn_perm(kMag, hi, 0x04010400u);  // (k1,k3)+136
    o.u.w = __builtin_amdgcn_perm(kMag, hi, 0x04030402u);  // (k5,k7)+136
    return o.f;
}

__device__ __forceinline__ bf16x8 unpack_bp(intx4 v)      // raw int4x4 path
{
    uint32_t p0 = __builtin_amdgcn_perm((uint32_t)v.y, (uint32_t)v.x, 0x0C0C0400u);
    uint32_t p1 = __builtin_amdgcn_perm((uint32_t)v.w, (uint32_t)v.z, 0x04000C0Cu);
    return unpack_b2((p0 | p1) ^ 0x88888888u);
}

#define DSR(D, AD, OFF) \
    asm volatile("ds_read_b128 %0, %1 offset:" OFF : "=v"(D) : "v"(AD))

#define PHASE_TAIL(BPC, UNPACK, O0,O1,O2,O3,O4,O5,O6,O7)                      \
        asm volatile("s_waitcnt vmcnt(12)" ::: "memory");                     \
        __builtin_amdgcn_sched_barrier(0);                                    \
        intx4 afr[8];                                                         \
        DSR(afr[0], dsBase, O0); DSR(afr[1], dsBase, O1);                     \
        DSR(afr[2], dsBase, O2); DSR(afr[3], dsBase, O3);                     \
        DSR(afr[4], dsBase, O4); DSR(afr[5], dsBase, O5);                     \
        DSR(afr[6], dsBase, O6); DSR(afr[7], dsBase, O7);                     \
        bf16x8 bfr[4];                                                        \
        _Pragma("unroll")                                                     \
        for (int ni = 0; ni < 4; ++ni) bfr[ni] = UNPACK(BPC[ni]);             \
        asm volatile("s_waitcnt lgkmcnt(4)" ::: "memory");                    \
        __builtin_amdgcn_sched_barrier(0);                                    \
        __builtin_amdgcn_s_setprio(1);                                        \
        _Pragma("unroll")                                                     \
        for (int mi = 0; mi < 4; ++mi) {                                      \
            const bf16x8 af = __builtin_bit_cast(bf16x8, afr[mi]);            \
            _Pragma("unroll")                                                 \
            for (int ni = 0; ni < 4; ++ni)                                    \
                acc[mi][ni] = __builtin_amdgcn_mfma_f32_16x16x32_bf16(        \
                    af, bfr[ni], acc[mi][ni], 0, 0, 0);                       \
        }                                                                     \
        asm volatile("s_waitcnt lgkmcnt(0)" ::: "memory");                    \
        __builtin_amdgcn_sched_barrier(0);                                    \
        _Pragma("unroll")                                                     \
        for (int mi = 4; mi < 8; ++mi) {                                      \
            const bf16x8 af = __builtin_bit_cast(bf16x8, afr[mi]);            \
            _Pragma("unroll")                                                 \
            for (int ni = 0; ni < 4; ++ni)                                    \
                acc[mi][ni] = __builtin_amdgcn_mfma_f32_16x16x32_bf16(        \
                    af, bfr[ni], acc[mi][ni], 0, 0, 0);                       \
        }                                                                     \
        __builtin_amdgcn_s_setprio(0);

#define PHASE_DMA(J, WOFF)                                                    \
        const int pA = (kb + (J) + 3) & (NPH - 1);                            \
        _Pragma("unroll")                                                     \
        for (int i = 0; i < 4; ++i)                                           \
            __builtin_amdgcn_global_load_lds(                                 \
                (const AS1 void*)(Agp + (size_t)i * 262144 + (size_t)pA * 32),\
                (AS3 void*)(sA + (WOFF) + i * 2048 + wave * 512), 16, 0, 0);

// B2 variant phase
#define PHASE_B2(J, BPC, BPN, WOFF, O0,O1,O2,O3,O4,O5,O6,O7)                  \
    {                                                                         \
        __builtin_amdgcn_s_barrier();                                         \
        asm volatile("" ::: "memory");                                        \
        const int pB = (kb + (J) + 1) & (NPH - 1);                            \
        const int bPh = ((pB >> 1) << 5) + ((pB & 1) << 2);                   \
        _Pragma("unroll")                                                     \
        for (int ni = 0; ni < 4; ++ni)                                        \
            BPN[ni] = *(const uint32_t*)(B2 + b2Off[ni] + bPh);               \
        __builtin_amdgcn_sched_barrier(0);                                    \
        PHASE_DMA(J, WOFF)                                                    \
        PHASE_TAIL(BPC, unpack_b2, O0,O1,O2,O3,O4,O5,O6,O7)                   \
    }

// direct-Bp variant phase (r6 fallback)
#define PHASE_BP(J, BPC, BPN, WOFF, O0,O1,O2,O3,O4,O5,O6,O7)                  \
    {                                                                         \
        __builtin_amdgcn_s_barrier();                                         \
        asm volatile("" ::: "memory");                                        \
        const int pB = (kb + (J) + 1) & (NPH - 1);                            \
        _Pragma("unroll")                                                     \
        for (int ni = 0; ni < 4; ++ni)                                        \
            BPN[ni] = *(const intx4*)(Bp + bOff[ni] + pB * 16);               \
        __builtin_amdgcn_sched_barrier(0);                                    \
        PHASE_DMA(J, WOFF)                                                    \
        PHASE_TAIL(BPC, unpack_bp, O0,O1,O2,O3,O4,O5,O6,O7)                   \
    }

// common kernel preamble (addressing, swizzle, acc init)
#define GEMM_PREAMBLE                                                         \
    __shared__ bf16_t sA[4 * 256 * BKP];                                      \
    const int t = threadIdx.x;                                                \
    const int wave = t >> 6;                                                  \
    const int lane = t & 63;                                                  \
    const int fm = lane & 15;                                                 \
    const int quad = lane >> 4;                                               \
    const int nBase = blockIdx.x * 128;                                       \
    const int mBase = blockIdx.y * 256;                                       \
    const int wL = lane >> 3;                                                 \
    const int sL = ((lane & 7) - wL) & 7;                                     \
    const int rL = 2 * wL + (sL >> 2);                                        \
    const int cL = sL & 3;                                                    \
    const uint32_t gAbase =                                                   \
        (uint32_t)(mBase + wave * 16 + rL) * K_DIM + (uint32_t)(cL << 3);     \
    const bf16_t* Agp = A + gAbase;                                           \
    const int wm = (wave >> 1) * 128;                                         \
    const int wn = (wave & 1) * 64;                                           \
    const int wR = fm >> 1;                                                   \
    const int spR = (((fm & 1) * 4 + quad) + wR) & 7;                         \
    const uint32_t dsBase =                                                   \
        (uint32_t)(size_t)(AS3 bf16_t*)sA +                                   \
        (uint32_t)(wm * 64 + wR * 128 + spR * 16);                            \
    floatx4 acc[8][4];                                                        \
    _Pragma("unroll")                                                         \
    for (int mi = 0; mi < 8; ++mi)                                            \
        _Pragma("unroll")                                                     \
        for (int ni = 0; ni < 4; ++ni)                                        \
            acc[mi][ni] = (floatx4){0.f, 0.f, 0.f, 0.f};

#define GEMM_PRO_DMA                                                          \
    _Pragma("unroll")                                                         \
    for (int pp = 0; pp < 3; ++pp)                                            \
        _Pragma("unroll")                                                     \
        for (int i = 0; i < 4; ++i)                                           \
            __builtin_amdgcn_global_load_lds(                                 \
                (const AS1 void*)(Agp + (size_t)i * 262144 + (size_t)pp * 32),\
                (AS3 void*)(sA + pp * 8192 + i * 2048 + wave * 512), 16, 0, 0);\
    asm volatile("s_waitcnt vmcnt(0) lgkmcnt(0)" ::: "memory");               \
    __builtin_amdgcn_sched_barrier(0);                                        \
    __builtin_amdgcn_s_barrier();                                             \
    asm volatile("" ::: "memory");

#define GEMM_EPILOGUE                                                         \
    _Pragma("unroll")                                                         \
    for (int mi = 0; mi < 8; ++mi) {                                          \
        const int m0 = mBase + wm + mi * 16 + quad * 4;                       \
        float cr[4];                                                          \
        _Pragma("unroll")                                                     \
        for (int r = 0; r < 4; ++r) cr[r] = crow[m0 + r];                     \
        _Pragma("unroll")                                                     \
        for (int ni = 0; ni < 4; ++ni) {                                      \
            const int n = nBase + wn + ni * 16 + fm;                          \
            const float bn = bias[n];                                         \
            _Pragma("unroll")                                                 \
            for (int r = 0; r < 4; ++r)                                       \
                __builtin_nontemporal_store(acc[mi][ni][r] + bn - cr[r],      \
                                            &out[(size_t)(m0 + r) * N_DIM + n]);\
        }                                                                     \
    }

// ---------------------------------------------------------------------------
__global__ __launch_bounds__(256, 2) void k_gemm_b2(
    const bf16_t* __restrict__ A,
    const uint8_t* __restrict__ B2,
    const float* __restrict__ bias,
    const float* __restrict__ crow,
    float* __restrict__ out)
{
    GEMM_PREAMBLE
    size_t b2Off[4];
#pragma unroll
    for (int ni = 0; ni < 4; ++ni)
        b2Off[ni] = (size_t)(nBase + wn + ni * 16 + fm) * (K_DIM / 2) + quad * 8;

    uint32_t bpA[4], bpB[4];
#pragma unroll
    for (int ni = 0; ni < 4; ++ni)
        bpA[ni] = *(const uint32_t*)(B2 + b2Off[ni]);
    __builtin_amdgcn_sched_barrier(0);
    GEMM_PRO_DMA

#pragma unroll 1
    for (int kb = 0; kb < NPH; kb += 4) {
        PHASE_B2(0, bpA, bpB, 24576, "0","1024","2048","3072","4096","5120","6144","7168")
        PHASE_B2(1, bpB, bpA, 0,     "16384","17408","18432","19456","20480","21504","22528","23552")
        PHASE_B2(2, bpA, bpB, 8192,  "32768","33792","34816","35840","36864","37888","38912","39936")
        PHASE_B2(3, bpB, bpA, 16384, "49152","50176","51200","52224","53248","54272","55296","56320")
    }
    GEMM_EPILOGUE
}

// r6-proven fallback: direct Bp loads (runs when ws_size can't hold B2)
__global__ __launch_bounds__(256, 2) void k_gemm_bp(
    const bf16_t* __restrict__ A,
    const int* __restrict__ Bp,
    const float* __restrict__ bias,
    const float* __restrict__ crow,
    float* __restrict__ out)
{
    GEMM_PREAMBLE
    int bOff[4];
#pragma unroll
    for (int ni = 0; ni < 4; ++ni)
        bOff[ni] = (nBase + wn + ni * 16 + fm) * (K_DIM / 2) + quad * 4;

    intx4 bpA[4], bpB[4];
#pragma unroll
    for (int ni = 0; ni < 4; ++ni)
        bpA[ni] = *(const intx4*)(Bp + bOff[ni]);
    __builtin_amdgcn_sched_barrier(0);
    GEMM_PRO_DMA

#pragma unroll 1
    for (int kb = 0; kb < NPH; kb += 4) {
        PHASE_BP(0, bpA, bpB, 24576, "0","1024","2048","3072","4096","5120","6144","7168")
        PHASE_BP(1, bpB, bpA, 0,     "16384","17408","18432","19456","20480","21504","22528","23552")
        PHASE_BP(2, bpA, bpB, 8192,  "32768","33792","34816","35840","36864","37888","38912","39936")
        PHASE_BP(3, bpB, bpA, 16384, "49152","50176","51200","52224","53248","54272","55296","56320")
    }
    GEMM_EPILOGUE
}

// ---------------------------------------------------------------------------
extern "C" void kernel_launch(void* const* d_in, const int* in_sizes, int n_in,
                              void* d_out, int out_size, void* d_ws, size_t ws_size,
                              hipStream_t stream)
{
    const float* x      = (const float*)d_in[0];
    const int*   pw     = (const int*)d_in[1];
    const float* scales = (const float*)d_in[2];
    const float* zps    = (const float*)d_in[3];
    const float* bias   = (const float*)d_in[4];
    float* out = (float*)d_out;

    char* ws = (char*)d_ws;
    bf16_t*  xs   = (bf16_t*)ws;               // 4096*4096*2 = 33554432 B
    float*   crow = (float*)(ws + 33554432);   // 4096*4      = 16384 B
    uint8_t* B2   = (uint8_t*)(ws + 33570816); // 11008*2048  = 22544384 B
    const size_t WS_NEED_B2 = 33570816u + 22544384u;   // 56115200

    hipLaunchKernelGGL(k_prescale, dim3(M_DIM / 4), dim3(256), 0, stream,
                       x, scales, zps, xs, crow);

    if (ws_size >= WS_NEED_B2) {
        // repacked-B path: B stream shrinks 90 -> 22.5 MB (L3-resident)
        hipLaunchKernelGGL(k_repack, dim3(11008 * 64 / 256), dim3(256), 0, stream,
                           pw, B2);
        hipLaunchKernelGGL(k_gemm_b2, dim3(N_DIM / 128, M_DIM / 256), dim3(256), 0, stream,
                           (const bf16_t*)xs, B2, bias, crow, out);
    } else {
        // r6-proven fallback: direct Bp loads, workspace footprint 33.57 MB
        hipLaunchKernelGGL(k_gemm_bp, dim3(N_DIM / 128, M_DIM / 256), dim3(256), 0, stream,
                           (const bf16_t*)xs, pw, bias, crow, out);
    }
}